// Round 8
// baseline (128.096 us; speedup 1.0000x reference)
//
#include <hip/hip_runtime.h>
#include <hip/hip_fp16.h>

#define BATCH 8192
#define NNB 100
#define NDEV 1000000

// Original row-id space (tails, dev1): lang 0-49, plat 50-54, os 55-84,
// country 85-284, carrier 285-784, brand 785-2784, plat_os 2785-2884.
#define NROWS 2885
#define NP2HALF (NROWS * 64)   // dev1 interleaved table elems

// Merged main-table geometry (msg path): row = merged id, 64 f16 per row.
//   lpo (lang*150+plat*30+os): rows 0..7499
//   country: 7500..7699  carrier: 7700..8199  brand: 8200..10199
//   plat_os: 10200..10299
#define LPO_ROWS 7500
#define MAIN_ROWS 10300
#define MAIN_ELEMS (MAIN_ROWS * 64)   // 659200 f16 = 1.29 MB

// Static device storage (graph-capture safe).
__device__ __half  g_Pmain[MAIN_ELEMS];   // msg main dims 0..63, f16, 128B rows
__device__ uint2   g_Ptail[NROWS];        // msg tail: {h2(d64,d65), h2(d66,0)}
__device__ __half2 g_P2dev1[NP2HALF];     // dev1 interleaved (256B rows)
__device__ float g_w0b_msg[256];    // [0:67]=W[:,0], [67:134]=b, rest 0
__device__ float g_w0b_dev1[256];
__device__ uint4 g_pack[NDEV];      // {cont_f32, lo_idx, hi_idx, 0}
// Transposed weights, padded to output-stride 64 (zeros beyond O).
__device__ float g_Wt_ch1[46 * 64];
__device__ float g_Wt_dev2[67 * 64];
__device__ float g_Wt_fus[94 * 64];
__device__ float g_Wt_c1[106 * 64];
__device__ float g_Wt_c2[63 * 64];
__device__ float g_bpad[5 * 64];

__device__ __forceinline__ float rl(float v, int k) {
    return __uint_as_float(__builtin_amdgcn_readlane(__float_as_uint(v), (unsigned)k));
}

// ---------------------------------------------------------------------------
// Kernel A: pack device rows + build all derived tables.
// Segments: NDEV pack | 480000 lpo | 179200 other mains | 2885 tails |
//           184640 dev1 | 24064 Wt | 320 bias | 268 w0b
// ---------------------------------------------------------------------------
__global__ __launch_bounds__(256) void prep_kernel(
    const float* __restrict__ devf,
    const float* __restrict__ lang, const float* __restrict__ plat,
    const float* __restrict__ osb, const float* __restrict__ country,
    const float* __restrict__ carrier, const float* __restrict__ brand,
    const float* __restrict__ plat_os,
    const float* __restrict__ Wmsg, const float* __restrict__ bmsg,
    const float* __restrict__ Wdev1, const float* __restrict__ bdev1,
    const float* __restrict__ Wch1, const float* __restrict__ bch1,
    const float* __restrict__ Wdev2, const float* __restrict__ bdev2,
    const float* __restrict__ Wfus, const float* __restrict__ bfus,
    const float* __restrict__ Wc1, const float* __restrict__ bc1,
    const float* __restrict__ Wc2, const float* __restrict__ bc2)
{
    long long gidx = (long long)blockIdx.x * 256 + threadIdx.x;
    if (gidx < NDEV) {
        int idx = (int)gidx;
        const float4* dr = (const float4*)(devf + (size_t)idx * 8);
        float4 a = dr[0], b4 = dr[1];
        unsigned lo = (unsigned)a.y | ((unsigned)a.z << 8)
                    | ((unsigned)a.w << 16) | ((unsigned)b4.w << 24);
        unsigned hi = (unsigned)b4.x | ((unsigned)b4.y << 9)
                    | ((unsigned)b4.z << 20);
        g_pack[idx] = make_uint4(__float_as_uint(a.x), lo, hi, 0u);
        return;
    }
    int q = (int)(gidx - NDEV);

    if (q < 480000) {                       // merged lpo main table
        int r = q >> 6, d = q & 63;
        int lg = r / 150, rem = r - lg * 150;
        int pl = rem / 30, os_ = rem - pl * 30;
        const float* W = Wmsg + d * 113;
        const float* el = lang + lg * 16;
        const float* ep = plat + pl * 16;
        const float* eo = osb + os_ * 16;
        float s = 0.f;
#pragma unroll
        for (int j = 0; j < 16; j++)
            s += el[j] * W[1 + j] + ep[j] * W[17 + j] + eo[j] * W[33 + j];
        g_Pmain[q] = __float2half(s);
        return;
    }
    q -= 480000;
    if (q < 179200) {                       // country/carrier/brand/plat_os mains
        const float* tab; int C, base;
        if (q < 12800)       { tab = country; C = 49; base = 0; }
        else if (q < 44800)  { tab = carrier; C = 65; base = 12800; }
        else if (q < 172800) { tab = brand;   C = 81; base = 44800; }
        else                 { tab = plat_os; C = 97; base = 172800; }
        int q2 = q - base, r = q2 >> 6, d = q2 & 63;
        const float* e = tab + r * 16;
        const float* W = Wmsg + d * 113 + C;
        float s = 0.f;
#pragma unroll
        for (int j = 0; j < 16; j++) s += e[j] * W[j];
        g_Pmain[480000 + q] = __float2half(s);
        return;
    }
    q -= 179200;
    if (q < NROWS) {                        // msg tail rows (dims 64..66)
        int row = q, t, r;
        if (row < 50)        { t = 0; r = row; }
        else if (row < 55)   { t = 1; r = row - 50; }
        else if (row < 85)   { t = 2; r = row - 55; }
        else if (row < 285)  { t = 3; r = row - 85; }
        else if (row < 785)  { t = 4; r = row - 285; }
        else if (row < 2785) { t = 5; r = row - 785; }
        else                 { t = 6; r = row - 2785; }
        const float* tab;
        switch (t) {
            case 0: tab = lang; break;    case 1: tab = plat; break;
            case 2: tab = osb; break;     case 3: tab = country; break;
            case 4: tab = carrier; break; case 5: tab = brand; break;
            default: tab = plat_os;
        }
        const float* e = tab + r * 16;
        float v[3];
#pragma unroll
        for (int d = 0; d < 3; d++) {
            const float* W = Wmsg + (64 + d) * 113 + 1 + 16 * t;
            float s = 0.f;
#pragma unroll
            for (int j = 0; j < 16; j++) s += e[j] * W[j];
            v[d] = s;
        }
        __half2 p0 = __halves2half2(__float2half(v[0]), __float2half(v[1]));
        __half2 p1 = __halves2half2(__float2half(v[2]), __float2half(0.f));
        g_Ptail[q] = make_uint2(*(unsigned*)&p0, *(unsigned*)&p1);
        return;
    }
    q -= NROWS;
    if (q < NP2HALF) {                      // dev1 interleaved table
        int row = q >> 6, l = q & 63, t, r;
        if (row < 50)        { t = 0; r = row; }
        else if (row < 55)   { t = 1; r = row - 50; }
        else if (row < 85)   { t = 2; r = row - 55; }
        else if (row < 285)  { t = 3; r = row - 85; }
        else if (row < 785)  { t = 4; r = row - 285; }
        else if (row < 2785) { t = 5; r = row - 785; }
        else                 { t = 6; r = row - 2785; }
        const float* tab;
        switch (t) {
            case 0: tab = lang; break;    case 1: tab = plat; break;
            case 2: tab = osb; break;     case 3: tab = country; break;
            case 4: tab = carrier; break; case 5: tab = brand; break;
            default: tab = plat_os;
        }
        const float* e = tab + r * 16;
        const float* Wm = Wdev1 + l * 113 + 1 + 16 * t;
        float m = 0.f;
#pragma unroll
        for (int j = 0; j < 16; j++) m += e[j] * Wm[j];
        float tl = 0.f;
        if (l < 3) {
            const float* Wt2 = Wdev1 + (64 + l) * 113 + 1 + 16 * t;
#pragma unroll
            for (int j = 0; j < 16; j++) tl += e[j] * Wt2[j];
        }
        g_P2dev1[q] = __halves2half2(__float2half(m), __float2half(tl));
        return;
    }
    int l = q - NP2HALF;
    if (l < 2944) { int k = l >> 6, o = l & 63; g_Wt_ch1[l]  = (o < 27) ? Wch1[o * 46 + k]  : 0.f; return; }
    l -= 2944;
    if (l < 4288) { int k = l >> 6, o = l & 63; g_Wt_dev2[l] = (o < 50) ? Wdev2[o * 67 + k] : 0.f; return; }
    l -= 4288;
    if (l < 6016) { int k = l >> 6, o = l & 63; g_Wt_fus[l]  = (o < 56) ? Wfus[o * 94 + k]  : 0.f; return; }
    l -= 6016;
    if (l < 6784) { int k = l >> 6, o = l & 63; g_Wt_c1[l]   = (o < 63) ? Wc1[o * 106 + k]  : 0.f; return; }
    l -= 6784;
    if (l < 4032) { int k = l >> 6, o = l & 63; g_Wt_c2[l]   = (o < 31) ? Wc2[o * 63 + k]   : 0.f; return; }
    l -= 4032;
    if (l < 320) {
        int which = l >> 6, o = l & 63;
        const float* b; int O;
        switch (which) {
            case 0: b = bch1; O = 27; break;  case 1: b = bdev2; O = 50; break;
            case 2: b = bfus; O = 56; break;  case 3: b = bc1; O = 63; break;
            default: b = bc2; O = 31;
        }
        g_bpad[l] = (o < O) ? b[o] : 0.f;
        return;
    }
    l -= 320;
    if (l < 268) {
        int which = l / 134, k = l - which * 134;
        float* dst = which ? g_w0b_dev1 : g_w0b_msg;
        const float* W = which ? Wdev1 : Wmsg;
        const float* b = which ? bdev1 : bmsg;
        dst[k] = (k < 67) ? W[k * 113] : b[k - 67];
    }
}

// ---------------------------------------------------------------------------
// Kernel B: one wave per edge (4 edges / 256-thread block).
// Main loop (dims 0..63): 5 gathers/neighbor from 128B f16 rows (merged lpo).
// Tail dims (64..66): per-lane side pass over LDS-resident 23KB tail table,
// then one cross-lane reduce. Phase 2: per-edge MLP in registers.
// ---------------------------------------------------------------------------
__global__ __launch_bounds__(256) void fused_kernel(
    const float* __restrict__ combin_feats, const float* __restrict__ chemb,
    const int* __restrict__ edges, const int* __restrict__ neibrs,
    const float* __restrict__ Wc3, const float* __restrict__ bc3,
    float* __restrict__ out)
{
    __shared__ uint2 s_tail[NROWS];
    int gid = blockIdx.x * 256 + threadIdx.x;
    int e = gid >> 6;
    int lane = threadIdx.x & 63;
    int eu = __builtin_amdgcn_readfirstlane(e);

    // Per-lane neighbor descriptors (for the tail pass): lane j -> nbr j, 64+j.
    const int* nb = neibrs + (size_t)eu * NNB;
    int n0 = nb[lane];
    int i1 = 64 + lane; if (i1 >= NNB) i1 = NNB - 1;
    int n1 = nb[i1];
    uint4 pkA = g_pack[n0];
    uint4 pkB = g_pack[n1];

    // Preload tail table to LDS (23 KB).
    for (int i = threadIdx.x; i < NROWS; i += 256) s_tail[i] = g_Ptail[i];
    __syncthreads();

    float mw0 = g_w0b_msg[lane];
    float mb  = g_w0b_msg[67 + lane];

    const __half* Pm = g_Pmain + lane;
    float acc0 = 0.f;

    // ---- Phase 1 main dims: uniform descriptor groups (R4 skeleton) ----
#define MBODY(R)                                                              \
    {                                                                         \
        unsigned lo = (R).y, hi = (R).z;                                      \
        float cont = __uint_as_float((R).x);                                  \
        int blpo = ((int)(lo & 255u) * 150 + (int)((lo >> 8) & 255u) * 30     \
                    + (int)((lo >> 16) & 255u)) << 6;                         \
        int bcty = (7500  + (int)(hi & 511u)) << 6;                           \
        int bcar = (7700  + (int)((hi >> 9) & 511u)) << 6;                    \
        int bbrd = (8200  + (int)(hi >> 20)) << 6;                            \
        int bpo  = (10200 + (int)(lo >> 24)) << 6;                            \
        __half h0 = Pm[blpo], h1 = Pm[bcty], h2 = Pm[bcar];                   \
        __half h3 = Pm[bbrd], h4 = Pm[bpo];                                   \
        float sum = __half2float(__hadd(__hadd(__hadd(h0, h1),                \
                                               __hadd(h2, h3)), h4));         \
        acc0 += fmaxf(fmaf(cont, mw0, mb) + sum, 0.f);                        \
    }

    const int4* nb4 = (const int4*)(neibrs + (size_t)eu * NNB);
    int4 nn = nb4[0];
    uint4 c0 = g_pack[nn.x], c1 = g_pack[nn.y];
    uint4 c2 = g_pack[nn.z], c3 = g_pack[nn.w];
#pragma unroll 1
    for (int g = 0; g < NNB / 4 - 1; ++g) {
        int4 nx = nb4[g + 1];
        uint4 m0 = g_pack[nx.x], m1 = g_pack[nx.y];
        uint4 m2 = g_pack[nx.z], m3 = g_pack[nx.w];
        MBODY(c0) MBODY(c1) MBODY(c2) MBODY(c3)
        c0 = m0; c1 = m1; c2 = m2; c3 = m3;
    }
    MBODY(c0) MBODY(c1) MBODY(c2) MBODY(c3)
#undef MBODY

    float msg_a = acc0 * 0.01f;

    // ---- Phase 1 tail dims (64..66): per-lane over LDS tail table ----
    float w064 = g_w0b_msg[64], w065 = g_w0b_msg[65], w066 = g_w0b_msg[66];
    float bb64 = g_w0b_msg[131], bb65 = g_w0b_msg[132], bb66 = g_w0b_msg[133];
    float a64 = 0.f, a65 = 0.f, a66 = 0.f;
#define TBODY(PK, VALID)                                                      \
    {                                                                         \
        unsigned lo = (PK).y, hi = (PK).z;                                    \
        float cont = __uint_as_float((PK).x);                                 \
        uint2 t0 = s_tail[(int)(lo & 255u)];                                  \
        uint2 t1 = s_tail[50 + (int)((lo >> 8) & 255u)];                      \
        uint2 t2 = s_tail[55 + (int)((lo >> 16) & 255u)];                     \
        uint2 t3 = s_tail[85 + (int)(hi & 511u)];                             \
        uint2 t4 = s_tail[285 + (int)((hi >> 9) & 511u)];                     \
        uint2 t5 = s_tail[785 + (int)(hi >> 20)];                             \
        uint2 t6 = s_tail[2785 + (int)(lo >> 24)];                            \
        __half2 sA = __hadd2(__hadd2(__hadd2(*(__half2*)&t0.x, *(__half2*)&t1.x), \
                                     __hadd2(*(__half2*)&t2.x, *(__half2*)&t3.x)), \
                             __hadd2(__hadd2(*(__half2*)&t4.x, *(__half2*)&t5.x), \
                                     *(__half2*)&t6.x));                      \
        __half2 sB = __hadd2(__hadd2(__hadd2(*(__half2*)&t0.y, *(__half2*)&t1.y), \
                                     __hadd2(*(__half2*)&t2.y, *(__half2*)&t3.y)), \
                             __hadd2(__hadd2(*(__half2*)&t4.y, *(__half2*)&t5.y), \
                                     *(__half2*)&t6.y));                      \
        float2 fA = __half22float2(sA);                                       \
        float f66 = __half2float(__low2half(sB));                             \
        float v64 = fmaf(cont, w064, bb64) + fA.x;                            \
        float v65 = fmaf(cont, w065, bb65) + fA.y;                            \
        float v66 = fmaf(cont, w066, bb66) + f66;                             \
        if (VALID) {                                                          \
            a64 += fmaxf(v64, 0.f);                                           \
            a65 += fmaxf(v65, 0.f);                                           \
            a66 += fmaxf(v66, 0.f);                                           \
        }                                                                     \
    }
    TBODY(pkA, true)
    TBODY(pkB, (lane < NNB - 64))
#undef TBODY
    for (int off = 32; off; off >>= 1) {
        a64 += __shfl_xor(a64, off);
        a65 += __shfl_xor(a65, off);
        a66 += __shfl_xor(a66, off);
    }
    float msg_b = ((lane == 1) ? a65 : (lane == 2) ? a66 : a64) * 0.01f;

    // ---- Phase 2: per-edge MLP, all activations in registers ----
    int e0 = edges[2 * eu], e1 = edges[2 * eu + 1];

    const float* crow = combin_feats + (size_t)e0 * 31;
    int chid = (int)crow[30];
    float cx = 0.f;
    if (lane < 30)      cx = crow[lane];
    else if (lane < 46) cx = chemb[(size_t)chid * 16 + (lane - 30)];

    // d1 = relu(W_dev1 @ dev_x + b) via interleaved dev1 table
    float d1a, d1b;
    {
        uint4 r = g_pack[e1];
        unsigned lo = (unsigned)__builtin_amdgcn_readfirstlane((int)r.y);
        unsigned hi = (unsigned)__builtin_amdgcn_readfirstlane((int)r.z);
        float cont = __uint_as_float((unsigned)__builtin_amdgcn_readfirstlane((int)r.x));
        int b0 = ((int)(lo & 255u)) << 6;
        int b1 = (50   + (int)((lo >> 8) & 255u)) << 6;
        int b2 = (55   + (int)((lo >> 16) & 255u)) << 6;
        int b6 = (2785 + (int)(lo >> 24)) << 6;
        int b3 = (85   + (int)(hi & 511u)) << 6;
        int b4 = (285  + (int)((hi >> 9) & 511u)) << 6;
        int b5 = (785  + (int)(hi >> 20)) << 6;
        const __half2* Ql = g_P2dev1 + lane;
        __half2 h0 = Ql[b0], h1 = Ql[b1], h2 = Ql[b2];
        __half2 h3 = Ql[b3], h4 = Ql[b4], h5 = Ql[b5], h6 = Ql[b6];
        __half2 s01 = __hadd2(h0, h1), s23 = __hadd2(h2, h3), s45 = __hadd2(h4, h5);
        __half2 sh = __hadd2(__hadd2(s01, s23), __hadd2(s45, h6));
        float2 f = __half22float2(sh);
        float vm = fmaf(cont, g_w0b_dev1[lane], g_w0b_dev1[67 + lane]) + f.x;
        float vt = fmaf(cont, g_w0b_dev1[64 + lane], g_w0b_dev1[131 + lane]) + f.y;
        d1a = fmaxf(vm, 0.f);
        d1b = fmaxf(vt, 0.f);
    }

    // ch = relu(W_ch1 @ combin_x + b)   I=46, O=27
    float s = g_bpad[lane];
    for (int k = 0; k < 46; k++) s += rl(cx, k) * g_Wt_ch1[k * 64 + lane];
    float ch = fmaxf(s, 0.f);

    // d2 = relu(W_dev2 @ d1 + b)        I=67, O=50
    s = g_bpad[64 + lane];
    for (int k = 0; k < 64; k++) s += rl(d1a, k) * g_Wt_dev2[k * 64 + lane];
    for (int k = 0; k < 3; k++)  s += rl(d1b, k) * g_Wt_dev2[(64 + k) * 64 + lane];
    float d2 = fmaxf(s, 0.f);

    // fus = relu(W_fus @ [ch|msg] + b)  I=94, O=56
    s = g_bpad[128 + lane];
    for (int k = 0; k < 27; k++) s += rl(ch, k) * g_Wt_fus[k * 64 + lane];
    for (int k = 0; k < 64; k++) s += rl(msg_a, k) * g_Wt_fus[(27 + k) * 64 + lane];
    for (int k = 0; k < 3; k++)  s += rl(msg_b, k) * g_Wt_fus[(91 + k) * 64 + lane];
    float fus = fmaxf(s, 0.f);

    // h1 = relu(W_c1 @ [fus|d2] + b)    I=106, O=63
    s = g_bpad[192 + lane];
    for (int k = 0; k < 56; k++) s += rl(fus, k) * g_Wt_c1[k * 64 + lane];
    for (int k = 0; k < 50; k++) s += rl(d2, k) * g_Wt_c1[(56 + k) * 64 + lane];
    float h1 = fmaxf(s, 0.f);

    // h2 = relu(W_c2 @ h1 + b)          I=63, O=31
    s = g_bpad[256 + lane];
    for (int k = 0; k < 63; k++) s += rl(h1, k) * g_Wt_c2[k * 64 + lane];
    float h2 = fmaxf(s, 0.f);

    // out = W_c3 @ h2 + b  (wave butterfly reduction)
    float t = (lane < 31) ? h2 * Wc3[lane] : 0.f;
    for (int off = 32; off; off >>= 1) t += __shfl_xor(t, off);
    if (lane == 0) out[e] = t + bc3[0];
}

extern "C" void kernel_launch(void* const* d_in, const int* in_sizes, int n_in,
                              void* d_out, int out_size, void* d_ws, size_t ws_size,
                              hipStream_t stream) {
    const float* combin   = (const float*)d_in[0];
    const float* devf     = (const float*)d_in[1];
    const float* chemb    = (const float*)d_in[2];
    const float* lang     = (const float*)d_in[3];
    const float* plat     = (const float*)d_in[4];
    const float* osb      = (const float*)d_in[5];
    const float* country  = (const float*)d_in[6];
    const float* carrier  = (const float*)d_in[7];
    const float* brand    = (const float*)d_in[8];
    const float* plat_os  = (const float*)d_in[9];
    const float* Wch1 = (const float*)d_in[10]; const float* bch1 = (const float*)d_in[11];
    const float* Wmsg = (const float*)d_in[12]; const float* bmsg = (const float*)d_in[13];
    const float* Wfus = (const float*)d_in[14]; const float* bfus = (const float*)d_in[15];
    const float* Wdev1 = (const float*)d_in[16]; const float* bdev1 = (const float*)d_in[17];
    const float* Wdev2 = (const float*)d_in[18]; const float* bdev2 = (const float*)d_in[19];
    const float* Wc1 = (const float*)d_in[20]; const float* bc1 = (const float*)d_in[21];
    const float* Wc2 = (const float*)d_in[22]; const float* bc2 = (const float*)d_in[23];
    const float* Wc3 = (const float*)d_in[24]; const float* bc3 = (const float*)d_in[25];
    const int* edges  = (const int*)d_in[26];
    const int* neibrs = (const int*)d_in[27];
    float* out = (float*)d_out;

    // prep: NDEV + 480000 + 179200 + 2885 + 184640 + 24064 + 320 + 268
    long long prep_threads = (long long)NDEV + 480000 + 179200 + NROWS
                           + NP2HALF + 24064 + 320 + 268;
    int prep_blocks = (int)((prep_threads + 255) / 256);
    prep_kernel<<<prep_blocks, 256, 0, stream>>>(
        devf, lang, plat, osb, country, carrier, brand, plat_os,
        Wmsg, bmsg, Wdev1, bdev1, Wch1, bch1, Wdev2, bdev2,
        Wfus, bfus, Wc1, bc1, Wc2, bc2);

    fused_kernel<<<BATCH / 4, 256, 0, stream>>>(
        combin, chemb, edges, neibrs, Wc3, bc3, out);
}

// Round 10
// 113.795 us; speedup vs baseline: 1.1257x; 1.1257x over previous
//
#include <hip/hip_runtime.h>
#include <hip/hip_fp16.h>

#define BATCH 8192
#define NNB 100
#define NDEV 1000000

// --- merged main msg table (interleaved f16 pairs, 256B rows) ---
// row ids: lpo (lang*150+plat*30+os) 0..7499 | country 7500..7699 |
// carrier 7700..8199 | brand 8200..10199 | plat_os 10200..10299
#define MAIN_ROWS 10300
#define NP2M (MAIN_ROWS * 64)      // 659200 half2

// --- dev1 table keeps original 7-table row space (once per edge) ---
#define NROWS 2885
#define NP2HALF (NROWS * 64)

typedef _Float16 f16x2 __attribute__((ext_vector_type(2)));

// Static device storage (graph-capture safe).
__device__ __half2 g_P2m[NP2M];       // msg: {f16 d[l], f16 d[64+l]} per row
__device__ __half2 g_P2dev1[NP2HALF];
__device__ float g_w0b_msg[256];      // [0:67]=W[:,0], [67:134]=b, rest 0
__device__ float g_w0b_dev1[256];
__device__ uint4 g_pack[NDEV];        // {cont_f32, lo_idx, hi_idx, 0}
// Packed f16-pair weight tables: element = {f16 W[o][k0], f16 W[o][k1]}.
__device__ unsigned g_W2_ch1[23 * 64];
__device__ unsigned g_W2_dev2[34 * 64];
__device__ unsigned g_W2_fus[48 * 64];
__device__ unsigned g_W2_c1[53 * 64];
__device__ unsigned g_W2_c2[32 * 64];
__device__ float g_bpad[5 * 64];      // padded biases: ch1, dev2, fus, c1, c2

__device__ __forceinline__ unsigned pkh(float a, float b) {
    f16x2 v; v.x = (_Float16)a; v.y = (_Float16)b;
    return __builtin_bit_cast(unsigned, v);
}
__device__ __forceinline__ float dot2u(unsigned a, unsigned b, float c) {
#if __has_builtin(__builtin_amdgcn_fdot2)
    return __builtin_amdgcn_fdot2(__builtin_bit_cast(f16x2, a),
                                  __builtin_bit_cast(f16x2, b), c, false);
#else
    __half2 ha = *reinterpret_cast<__half2*>(&a);
    __half2 hb = *reinterpret_cast<__half2*>(&b);
    float2 fa = __half22float2(ha), fb = __half22float2(hb);
    return fmaf(fa.x, fb.x, fmaf(fa.y, fb.y, c));
#endif
}

// ---------------------------------------------------------------------------
// Kernel A: pack device rows + build all derived tables.
// Segments: NDEV pack | 480000 lpo | 179200 other mains | 184640 dev1 |
//           12160 W2 | 320 bias | 268 w0b
// ---------------------------------------------------------------------------
__global__ __launch_bounds__(256) void prep_kernel(
    const float* __restrict__ devf,
    const float* __restrict__ lang, const float* __restrict__ plat,
    const float* __restrict__ osb, const float* __restrict__ country,
    const float* __restrict__ carrier, const float* __restrict__ brand,
    const float* __restrict__ plat_os,
    const float* __restrict__ Wmsg, const float* __restrict__ bmsg,
    const float* __restrict__ Wdev1, const float* __restrict__ bdev1,
    const float* __restrict__ Wch1, const float* __restrict__ bch1,
    const float* __restrict__ Wdev2, const float* __restrict__ bdev2,
    const float* __restrict__ Wfus, const float* __restrict__ bfus,
    const float* __restrict__ Wc1, const float* __restrict__ bc1,
    const float* __restrict__ Wc2, const float* __restrict__ bc2)
{
    long long gidx = (long long)blockIdx.x * 256 + threadIdx.x;
    if (gidx < NDEV) {
        int idx = (int)gidx;
        const float4* dr = (const float4*)(devf + (size_t)idx * 8);
        float4 a = dr[0], b4 = dr[1];
        unsigned lo = (unsigned)a.y | ((unsigned)a.z << 8)
                    | ((unsigned)a.w << 16) | ((unsigned)b4.w << 24);
        unsigned hi = (unsigned)b4.x | ((unsigned)b4.y << 9)
                    | ((unsigned)b4.z << 20);
        g_pack[idx] = make_uint4(__float_as_uint(a.x), lo, hi, 0u);
        return;
    }
    int q = (int)(gidx - NDEV);

    if (q < 480000) {                        // merged lpo rows, interleaved
        int r = q >> 6, l = q & 63;
        int lg = r / 150, rem = r - lg * 150;
        int pl = rem / 30, os_ = rem - pl * 30;
        const float* el = lang + lg * 16;
        const float* ep = plat + pl * 16;
        const float* eo = osb + os_ * 16;
        const float* Wm = Wmsg + l * 113;
        float m = 0.f;
#pragma unroll
        for (int j = 0; j < 16; j++)
            m += el[j] * Wm[1 + j] + ep[j] * Wm[17 + j] + eo[j] * Wm[33 + j];
        float tl = 0.f;
        if (l < 3) {
            const float* Wt2 = Wmsg + (64 + l) * 113;
#pragma unroll
            for (int j = 0; j < 16; j++)
                tl += el[j] * Wt2[1 + j] + ep[j] * Wt2[17 + j] + eo[j] * Wt2[33 + j];
        }
        g_P2m[q] = __halves2half2(__float2half(m), __float2half(tl));
        return;
    }
    q -= 480000;
    if (q < 179200) {                        // country/carrier/brand/plat_os
        const float* tab; int C, base;
        if (q < 12800)       { tab = country; C = 49; base = 0; }
        else if (q < 44800)  { tab = carrier; C = 65; base = 12800; }
        else if (q < 172800) { tab = brand;   C = 81; base = 44800; }
        else                 { tab = plat_os; C = 97; base = 172800; }
        int q2 = q - base, r = q2 >> 6, l = q2 & 63;
        const float* e = tab + r * 16;
        const float* Wm = Wmsg + l * 113 + C;
        float m = 0.f;
#pragma unroll
        for (int j = 0; j < 16; j++) m += e[j] * Wm[j];
        float tl = 0.f;
        if (l < 3) {
            const float* Wt2 = Wmsg + (64 + l) * 113 + C;
#pragma unroll
            for (int j = 0; j < 16; j++) tl += e[j] * Wt2[j];
        }
        g_P2m[480000 + q] = __halves2half2(__float2half(m), __float2half(tl));
        return;
    }
    q -= 179200;
    if (q < NP2HALF) {                       // dev1 interleaved table
        int row = q >> 6, l = q & 63, t, r;
        if (row < 50)        { t = 0; r = row; }
        else if (row < 55)   { t = 1; r = row - 50; }
        else if (row < 85)   { t = 2; r = row - 55; }
        else if (row < 285)  { t = 3; r = row - 85; }
        else if (row < 785)  { t = 4; r = row - 285; }
        else if (row < 2785) { t = 5; r = row - 785; }
        else                 { t = 6; r = row - 2785; }
        const float* tab;
        switch (t) {
            case 0: tab = lang; break;    case 1: tab = plat; break;
            case 2: tab = osb; break;     case 3: tab = country; break;
            case 4: tab = carrier; break; case 5: tab = brand; break;
            default: tab = plat_os;
        }
        const float* e = tab + r * 16;
        const float* Wm = Wdev1 + l * 113 + 1 + 16 * t;
        float m = 0.f;
#pragma unroll
        for (int j = 0; j < 16; j++) m += e[j] * Wm[j];
        float tl = 0.f;
        if (l < 3) {
            const float* Wt2 = Wdev1 + (64 + l) * 113 + 1 + 16 * t;
#pragma unroll
            for (int j = 0; j < 16; j++) tl += e[j] * Wt2[j];
        }
        g_P2dev1[q] = __halves2half2(__float2half(m), __float2half(tl));
        return;
    }
    q -= NP2HALF;
    if (q < 12160) {                         // packed f16-pair weight tables
        const float* W; int O, I, p, k0, k1, oo; unsigned* dst; int base;
        if (q < 1472) {
            base = q; W = Wch1; O = 27; I = 46; p = base >> 6;
            k0 = 2 * p; k1 = 2 * p + 1; dst = g_W2_ch1;
        } else if (q < 3648) {
            base = q - 1472; W = Wdev2; O = 50; I = 67; p = base >> 6;
            if (p < 32)      { k0 = 2 * p; k1 = 2 * p + 1; }
            else if (p == 32){ k0 = 64; k1 = 65; }
            else             { k0 = 66; k1 = -1; }
            dst = g_W2_dev2;
        } else if (q < 6720) {
            base = q - 3648; W = Wfus; O = 56; I = 94; p = base >> 6;
            if (p < 14)      { k0 = 2 * p; k1 = 2 * p + 1;
                               if (k0 >= 27) k0 = -1; if (k1 >= 27) k1 = -1; }
            else if (p < 46) { k0 = 27 + 2 * (p - 14); k1 = k0 + 1; }
            else if (p == 46){ k0 = 91; k1 = 92; }
            else             { k0 = 93; k1 = -1; }
            dst = g_W2_fus;
        } else if (q < 10112) {
            base = q - 6720; W = Wc1; O = 63; I = 106; p = base >> 6;
            if (p < 28) { k0 = 2 * p; k1 = 2 * p + 1; }
            else        { k0 = 56 + 2 * (p - 28); k1 = k0 + 1; }
            dst = g_W2_c1;
        } else {
            base = q - 10112; W = Wc2; O = 31; I = 63; p = base >> 6;
            k0 = 2 * p; k1 = 2 * p + 1; if (k1 >= 63) k1 = -1;
            dst = g_W2_c2;
        }
        oo = base & 63;
        float w0 = (oo < O && k0 >= 0 && k0 < I) ? W[oo * I + k0] : 0.f;
        float w1 = (oo < O && k1 >= 0 && k1 < I) ? W[oo * I + k1] : 0.f;
        dst[base] = pkh(w0, w1);
        return;
    }
    q -= 12160;
    if (q < 320) {
        int which = q >> 6, o = q & 63;
        const float* b; int O;
        switch (which) {
            case 0: b = bch1; O = 27; break;  case 1: b = bdev2; O = 50; break;
            case 2: b = bfus; O = 56; break;  case 3: b = bc1; O = 63; break;
            default: b = bc2; O = 31;
        }
        g_bpad[q] = (o < O) ? b[o] : 0.f;
        return;
    }
    q -= 320;
    if (q < 268) {
        int which = q / 134, k = q - which * 134;
        float* dst = which ? g_w0b_dev1 : g_w0b_msg;
        const float* W = which ? Wdev1 : Wmsg;
        const float* b = which ? bdev1 : bmsg;
        dst[k] = (k < 67) ? W[k * 113] : b[k - 67];
    }
}

// ---------------------------------------------------------------------------
// Kernel B: one wave per edge (4 edges / 256-thread block).
// Phase 1: uniform s_load descriptor groups (1 ahead) + merged-lpo interleaved
//          table -> 5 gathers/neighbor.
// Phase 2: packed-f16 pair GEMVs via v_dot2_f32_f16 (f32 acc).
// CONVERGENCE RULE: every __shfl is executed unconditionally by the full wave
// (ds_bpermute reads from inactive lanes are undefined); lane-dependent
// selection happens on the already-shuffled VALUES only.
// ---------------------------------------------------------------------------
__global__ __launch_bounds__(256) void fused_kernel(
    const float* __restrict__ combin_feats, const float* __restrict__ chemb,
    const int* __restrict__ edges, const int* __restrict__ neibrs,
    const float* __restrict__ Wc3, const float* __restrict__ bc3,
    float* __restrict__ out)
{
    int gid = blockIdx.x * 256 + threadIdx.x;
    int e = gid >> 6;
    int lane = threadIdx.x & 63;
    int eu = __builtin_amdgcn_readfirstlane(e);

    float mw0  = g_w0b_msg[lane];
    float mb   = g_w0b_msg[67 + lane];
    float mw0b = g_w0b_msg[64 + lane];    // valid lane<3; finite otherwise
    float mbb  = g_w0b_msg[131 + lane];

    const __half2* Pm = g_P2m + lane;
    float acc0 = 0.f, acc1 = 0.f;

#define MBODY(R)                                                              \
    {                                                                         \
        unsigned lo = (R).y, hi = (R).z;                                      \
        float cont = __uint_as_float((R).x);                                  \
        int blpo = ((int)(lo & 255u) * 150 + (int)((lo >> 8) & 255u) * 30     \
                    + (int)((lo >> 16) & 255u)) << 6;                         \
        int bcty = (7500  + (int)(hi & 511u)) << 6;                           \
        int bcar = (7700  + (int)((hi >> 9) & 511u)) << 6;                    \
        int bbrd = (8200  + (int)(hi >> 20)) << 6;                            \
        int bpo  = (10200 + (int)(lo >> 24)) << 6;                            \
        __half2 h0 = Pm[blpo], h1 = Pm[bcty], h2 = Pm[bcar];                  \
        __half2 h3 = Pm[bbrd], h4 = Pm[bpo];                                  \
        __half2 sv = __hadd2(__hadd2(__hadd2(h0, h1), __hadd2(h2, h3)), h4);  \
        float2 f = __half22float2(sv);                                        \
        float vm = fmaf(cont, mw0, mb) + f.x;                                 \
        float vt = fmaf(cont, mw0b, mbb) + f.y;                               \
        acc0 += fmaxf(vm, 0.f);                                               \
        acc1 += fmaxf(vt, 0.f);                                               \
    }

    const int4* nb4 = (const int4*)(neibrs + (size_t)eu * NNB);
    int4 nn = nb4[0];
    uint4 c0 = g_pack[nn.x], c1 = g_pack[nn.y];
    uint4 c2 = g_pack[nn.z], c3 = g_pack[nn.w];
#pragma unroll 1
    for (int g = 0; g < NNB / 4 - 1; ++g) {
        int4 nx = nb4[g + 1];
        uint4 m0 = g_pack[nx.x], m1 = g_pack[nx.y];
        uint4 m2 = g_pack[nx.z], m3 = g_pack[nx.w];
        MBODY(c0) MBODY(c1) MBODY(c2) MBODY(c3)
        c0 = m0; c1 = m1; c2 = m2; c3 = m3;
    }
    MBODY(c0) MBODY(c1) MBODY(c2) MBODY(c3)
#undef MBODY

    float msg_a = acc0 * 0.01f;
    float msg_b = acc1 * 0.01f;   // lanes 0..2: dims 64..66

    // ---- Phase 2 ----
    int e0 = edges[2 * eu], e1 = edges[2 * eu + 1];

    const float* crow = combin_feats + (size_t)e0 * 31;
    int chid = (int)crow[30];
    float cx = 0.f;
    if (lane < 30)      cx = crow[lane];
    else if (lane < 46) cx = chemb[(size_t)chid * 16 + (lane - 30)];

    // d1 via dev1 interleaved table (once per edge)
    float d1a, d1b;
    {
        uint4 r = g_pack[e1];
        unsigned lo = (unsigned)__builtin_amdgcn_readfirstlane((int)r.y);
        unsigned hi = (unsigned)__builtin_amdgcn_readfirstlane((int)r.z);
        float cont = __uint_as_float((unsigned)__builtin_amdgcn_readfirstlane((int)r.x));
        int b0 = ((int)(lo & 255u)) << 6;
        int b1 = (50   + (int)((lo >> 8) & 255u)) << 6;
        int b2 = (55   + (int)((lo >> 16) & 255u)) << 6;
        int b6 = (2785 + (int)(lo >> 24)) << 6;
        int b3 = (85   + (int)(hi & 511u)) << 6;
        int b4 = (285  + (int)((hi >> 9) & 511u)) << 6;
        int b5 = (785  + (int)(hi >> 20)) << 6;
        const __half2* Ql = g_P2dev1 + lane;
        __half2 h0 = Ql[b0], h1 = Ql[b1], h2 = Ql[b2];
        __half2 h3 = Ql[b3], h4 = Ql[b4], h5 = Ql[b5], h6 = Ql[b6];
        __half2 sh = __hadd2(__hadd2(__hadd2(h0, h1), __hadd2(h2, h3)),
                             __hadd2(__hadd2(h4, h5), h6));
        float2 f = __half22float2(sh);
        float vm = fmaf(cont, g_w0b_dev1[lane], g_w0b_dev1[67 + lane]) + f.x;
        float vt = fmaf(cont, g_w0b_dev1[64 + lane], g_w0b_dev1[131 + lane]) + f.y;
        d1a = fmaxf(vm, 0.f);
        d1b = fmaxf(vt, 0.f);
    }

    // ch = relu(W_ch1 @ cx + b): 23 pairs.  (full-wave shfls)
    float cxa = __shfl(cx, (2 * lane) & 63);
    float cxb = __shfl(cx, (2 * lane + 1) & 63);
    int pk_cx = (int)pkh(cxa, cxb);
    float s = g_bpad[lane];
#pragma unroll
    for (int p = 0; p < 23; p++)
        s = dot2u((unsigned)__builtin_amdgcn_readlane(pk_cx, p),
                  g_W2_ch1[p * 64 + lane], s);
    float ch = fmaxf(s, 0.f);   // lanes >=27 are exactly 0 (zero weights+bias)

    // d2 = relu(W_dev2 @ d1 + b): 34 pairs (d1a 64 dims + d1b 3 dims)
    {
        float dA0 = __shfl(d1a, (2 * lane) & 63);
        float dA1 = __shfl(d1a, (2 * lane + 1) & 63);
        float dB0 = __shfl(d1b, (2 * lane) & 63);   // lane32->d1b[0], lane33->d1b[2]
        float dB1 = __shfl(d1b, 1);
        float a0 = (lane < 32) ? dA0 : dB0;
        float a1 = (lane < 32) ? dA1 : ((lane == 32) ? dB1 : 0.f);
        int pk_d1 = (int)pkh(a0, a1);
        s = g_bpad[64 + lane];
#pragma unroll
        for (int p = 0; p < 34; p++)
            s = dot2u((unsigned)__builtin_amdgcn_readlane(pk_d1, p),
                      g_W2_dev2[p * 64 + lane], s);
    }
    float d2 = fmaxf(s, 0.f);   // lanes >=50 exactly 0

    // fus = relu(W_fus @ [ch(27) | msg(67)] + b): 48 pairs
    {
        int j = lane - 14;
        float mA0 = __shfl(msg_a, (2 * j) & 63);
        float mA1 = __shfl(msg_a, (2 * j + 1) & 63);
        float mB0 = __shfl(msg_b, (2 * j) & 63);    // j=32->msg_b[0], j=33->msg_b[2]
        float mB1 = __shfl(msg_b, 1);
        float cv0 = __shfl(ch, (2 * lane) & 63);
        float cv1 = __shfl(ch, (2 * lane + 1) & 63);  // lane13 reads ch[27]==0
        float m0 = (j < 32) ? mA0 : mB0;
        float m1 = (j < 32) ? mA1 : ((j == 32) ? mB1 : 0.f);
        float f0 = (lane < 14) ? cv0 : m0;
        float f1 = (lane < 14) ? cv1 : m1;
        int pk_f = (int)pkh(f0, f1);
        s = g_bpad[128 + lane];
#pragma unroll
        for (int p = 0; p < 48; p++)
            s = dot2u((unsigned)__builtin_amdgcn_readlane(pk_f, p),
                      g_W2_fus[p * 64 + lane], s);
    }
    float fus = fmaxf(s, 0.f);  // lanes >=56 exactly 0

    // h1 = relu(W_c1 @ [fus(56) | d2(50)] + b): 53 pairs
    {
        float fA0 = __shfl(fus, (2 * lane) & 63);
        float fA1 = __shfl(fus, (2 * lane + 1) & 63);
        float dD0 = __shfl(d2, (2 * (lane - 28)) & 63);
        float dD1 = __shfl(d2, (2 * (lane - 28) + 1) & 63);
        float x0 = (lane < 28) ? fA0 : dD0;
        float x1 = (lane < 28) ? fA1 : dD1;
        int pk_x = (int)pkh(x0, x1);
        s = g_bpad[192 + lane];
#pragma unroll
        for (int p = 0; p < 53; p++)
            s = dot2u((unsigned)__builtin_amdgcn_readlane(pk_x, p),
                      g_W2_c1[p * 64 + lane], s);
    }
    float h1 = fmaxf(s, 0.f);   // lane 63 exactly 0

    // h2 = relu(W_c2 @ h1 + b): 32 pairs
    {
        float y0 = __shfl(h1, (2 * lane) & 63);
        float y1 = __shfl(h1, (2 * lane + 1) & 63);   // lane31 reads h1[63]==0
        int pk_y = (int)pkh(y0, y1);
        s = g_bpad[256 + lane];
#pragma unroll
        for (int p = 0; p < 32; p++)
            s = dot2u((unsigned)__builtin_amdgcn_readlane(pk_y, p),
                      g_W2_c2[p * 64 + lane], s);
    }
    float h2 = fmaxf(s, 0.f);

    // out = W_c3 @ h2 + b  (wave butterfly reduction, f32)
    float t = (lane < 31) ? h2 * Wc3[lane] : 0.f;
    for (int off = 32; off; off >>= 1) t += __shfl_xor(t, off);
    if (lane == 0) out[e] = t + bc3[0];
}

extern "C" void kernel_launch(void* const* d_in, const int* in_sizes, int n_in,
                              void* d_out, int out_size, void* d_ws, size_t ws_size,
                              hipStream_t stream) {
    const float* combin   = (const float*)d_in[0];
    const float* devf     = (const float*)d_in[1];
    const float* chemb    = (const float*)d_in[2];
    const float* lang     = (const float*)d_in[3];
    const float* plat     = (const float*)d_in[4];
    const float* osb      = (const float*)d_in[5];
    const float* country  = (const float*)d_in[6];
    const float* carrier  = (const float*)d_in[7];
    const float* brand    = (const float*)d_in[8];
    const float* plat_os  = (const float*)d_in[9];
    const float* Wch1 = (const float*)d_in[10]; const float* bch1 = (const float*)d_in[11];
    const float* Wmsg = (const float*)d_in[12]; const float* bmsg = (const float*)d_in[13];
    const float* Wfus = (const float*)d_in[14]; const float* bfus = (const float*)d_in[15];
    const float* Wdev1 = (const float*)d_in[16]; const float* bdev1 = (const float*)d_in[17];
    const float* Wdev2 = (const float*)d_in[18]; const float* bdev2 = (const float*)d_in[19];
    const float* Wc1 = (const float*)d_in[20]; const float* bc1 = (const float*)d_in[21];
    const float* Wc2 = (const float*)d_in[22]; const float* bc2 = (const float*)d_in[23];
    const float* Wc3 = (const float*)d_in[24]; const float* bc3 = (const float*)d_in[25];
    const int* edges  = (const int*)d_in[26];
    const int* neibrs = (const int*)d_in[27];
    float* out = (float*)d_out;

    // prep: NDEV + 480000 + 179200 + 184640 + 12160 + 320 + 268
    long long prep_threads = (long long)NDEV + 480000 + 179200 + NP2HALF
                           + 12160 + 320 + 268;
    int prep_blocks = (int)((prep_threads + 255) / 256);
    prep_kernel<<<prep_blocks, 256, 0, stream>>>(
        devf, lang, plat, osb, country, carrier, brand, plat_os,
        Wmsg, bmsg, Wdev1, bdev1, Wch1, bch1, Wdev2, bdev2,
        Wfus, bfus, Wc1, bc1, Wc2, bc2);

    fused_kernel<<<BATCH / 4, 256, 0, stream>>>(
        combin, chemb, edges, neibrs, Wc3, bc3, out);
}